// Round 9
// baseline (360.982 us; speedup 1.0000x reference)
//
#include <hip/hip_runtime.h>
#include <hip/hip_fp16.h>

// GCN forward — two-level counting-sort CSR (no global atomics, coalesced
// placement) + fp16 gather table (L2-resident) + half8-lane wave-per-node
// aggregation (32 rows in flight per wave). h@W2 and Wout fused in epilogues.
// N=100000, E=3200000, IN_C=128, HID=16, OUT=1.

constexpr int N_NODES = 100000;
constexpr int N_EDGES = 3200000;
constexpr int INC = 128;
constexpr int HID = 16;

constexpr int BSH  = 128;                       // nodes per bucket
constexpr int NBUK = (N_NODES + BSH - 1) / BSH; // 782
constexpr int NBLK = 1024;                      // edge-chunk blocks
constexpr int EPB  = N_EDGES / NBLK;            // 3125 edges/block (exact)
constexpr int BUFCAP = 6144;                    // LDS edge staging in sort2

// ---------------- pass 1: per-block LDS histogram (block-major out) -----------

__global__ __launch_bounds__(256) void k_hist1(const int* __restrict__ col,
                                               int* __restrict__ blkhist) {
    __shared__ int lh[NBUK];
    int tid = threadIdx.x, blk = blockIdx.x;
    for (int i = tid; i < NBUK; i += 256) lh[i] = 0;
    __syncthreads();
    int s = blk * EPB;
    for (int e = s + tid; e < s + EPB; e += 256)
        atomicAdd(&lh[col[e] >> 7], 1);          // LDS atomic
    __syncthreads();
    for (int i = tid; i < NBUK; i += 256)
        blkhist[blk * NBUK + i] = lh[i];         // coalesced
}

// ---------------- pass 2a: per-bucket scan over the 1024 block counts ---------

__global__ __launch_bounds__(1024) void k_colscan(const int* __restrict__ blkhist,
                                                  int* __restrict__ offs,
                                                  int* __restrict__ total) {
    __shared__ int sA[NBLK], sB[NBLK];
    int b = blockIdx.x, t = threadIdx.x;
    int v = blkhist[t * NBUK + b];
    sA[t] = v;
    __syncthreads();
    int* src = sA; int* dst = sB;
    for (int off = 1; off < NBLK; off <<= 1) {
        dst[t] = src[t] + ((t >= off) ? src[t - off] : 0);
        __syncthreads();
        int* tmp = src; src = dst; dst = tmp;
    }
    offs[b * NBLK + t] = src[t] - v;
    if (t == NBLK - 1) total[b] = src[NBLK - 1];
}

// ---------------- pass 2b: bucket starts (single block) ----------------

__global__ __launch_bounds__(1024) void k_bscan(const int* __restrict__ total,
                                                int* __restrict__ bstart) {
    __shared__ int s[1024];
    int t = threadIdx.x;
    int v = (t < NBUK) ? total[t] : 0;
    s[t] = v;
    __syncthreads();
    for (int off = 1; off < 1024; off <<= 1) {
        int u = (t >= off) ? s[t - off] : 0;
        __syncthreads();
        s[t] += u;
        __syncthreads();
    }
    if (t <= NBUK) bstart[t] = s[t] - v;         // bstart[NBUK] = E
}

// ---------------- pass 3: placement, LDS-staged bucket sort, coalesced out ----

__global__ __launch_bounds__(256) void k_place(const int* __restrict__ row,
                                               const int* __restrict__ col,
                                               const float* __restrict__ ew,
                                               const int* __restrict__ offs,
                                               const int* __restrict__ bstart,
                                               int2* __restrict__ pay) {
    __shared__ int2 spay[EPB];
    __shared__ unsigned short sbuk[EPB];
    __shared__ int lh[NBUK];
    __shared__ int gb[NBUK];
    __shared__ int sA[1024], sB[1024];
    int tid = threadIdx.x, blk = blockIdx.x;
    for (int i = tid; i < NBUK; i += 256) lh[i] = 0;
    __syncthreads();
    int s0 = blk * EPB;
    for (int j = tid; j < EPB; j += 256)
        atomicAdd(&lh[col[s0 + j] >> 7], 1);
    __syncthreads();
    for (int i = tid; i < 1024; i += 256) sA[i] = (i < NBUK) ? lh[i] : 0;
    __syncthreads();
    int* src = sA; int* dst = sB;
    for (int off = 1; off < 1024; off <<= 1) {
        for (int i = tid; i < 1024; i += 256)
            dst[i] = src[i] + ((i >= off) ? src[i - off] : 0);
        __syncthreads();
        int* tmp = src; src = dst; dst = tmp;
    }
    for (int i = tid; i < NBUK; i += 256) {
        int excl = src[i] - lh[i];
        gb[i] = bstart[i] + offs[i * NBLK + blk] - excl;
        lh[i] = excl;
    }
    __syncthreads();
    for (int j = tid; j < EPB; j += 256) {
        int e = s0 + j;
        int c = col[e];
        int b = c >> 7;
        int pos = atomicAdd(&lh[b], 1);
        spay[pos] = make_int2(((c & 127) << 17) | row[e], __float_as_int(ew[e]));
        sbuk[pos] = (unsigned short)b;
    }
    __syncthreads();
    for (int j = tid; j < EPB; j += 256) {
        int b = sbuk[j];
        pay[gb[b] + j] = spay[j];
    }
}

// ---------------- pass 4: in-bucket node sort (in place) + node_start + dinv --

__global__ __launch_bounds__(256) void k_sort2(const int* __restrict__ bstart,
                                               int2* __restrict__ pay,
                                               int* __restrict__ node_start,
                                               float* __restrict__ dinv) {
    __shared__ int2 buf[BUFCAP];
    __shared__ int cnt[BSH], sc[BSH], pos[BSH];
    __shared__ float dsum[BSH];
    int b = blockIdx.x, t = threadIdx.x;
    if (t < BSH) { cnt[t] = 0; dsum[t] = 1.0f; }   // 1.0 = self-loop weight
    __syncthreads();
    int s = bstart[b], e2 = bstart[b + 1];
    int m = e2 - s;
    for (int j = t; j < m; j += 256) {
        int2 pr = pay[s + j];
        buf[j] = pr;
        int d = pr.x >> 17;
        atomicAdd(&cnt[d], 1);
        atomicAdd(&dsum[d], __int_as_float(pr.y));
    }
    __syncthreads();
    int v = (t < BSH) ? cnt[t] : 0;
    if (t < BSH) sc[t] = v;
    __syncthreads();
    for (int off = 1; off < BSH; off <<= 1) {
        int u = (t >= off && t < BSH) ? sc[t - off] : 0;
        __syncthreads();
        if (t < BSH) sc[t] += u;
        __syncthreads();
    }
    if (t < BSH) {
        int excl = sc[t] - v;
        pos[t] = excl;
        int node = b * BSH + t;
        if (node <= N_NODES) node_start[node] = s + excl;
        if (node < N_NODES) dinv[node] = rsqrtf(dsum[t]);
    }
    if (t == 0 && b == 0) node_start[N_NODES] = N_EDGES;
    __syncthreads();
    for (int j = t; j < m; j += 256) {
        int2 pr = buf[j];
        int q = atomicAdd(&pos[pr.x >> 17], 1);
        pay[s + q] = make_int2(pr.x & 0x1FFFF, pr.y);
    }
}

// ---------------- GEMM x@W1, epilogue x dinv -> fp16: t1 = dinv ⊙ (x@W1) ------

__global__ __launch_bounds__(256) void k_gemm_in(const float* __restrict__ x,
                                                 const float* __restrict__ W1,
                                                 const float* __restrict__ dinv,
                                                 __half* __restrict__ t1) {
    __shared__ float ws[INC * HID];
    __shared__ float xs[16 * 129];
    int tid = threadIdx.x;
    int nb = blockIdx.x * 16;
    const float4* x4 = (const float4*)(x + (size_t)nb * INC);
    for (int j = tid; j < 512; j += 256) {
        float4 v = x4[j];
        int n = j >> 5, kq = (j & 31) << 2;
        float* d = &xs[n * 129 + kq];
        d[0] = v.x; d[1] = v.y; d[2] = v.z; d[3] = v.w;
    }
    for (int j = tid; j < 512; j += 256)
        ((float4*)ws)[j] = ((const float4*)W1)[j];
    __syncthreads();
    int ln = tid >> 4, c = tid & 15;
    float acc = 0.f;
#pragma unroll
    for (int k = 0; k < INC; ++k) acc += xs[ln * 129 + k] * ws[k * HID + c];
    int node = nb + ln;
    t1[(node << 4) + c] = __float2half(dinv[node] * acc);
}

// ---------------- layer-1 aggregation + bias/relu + fused h@W2 -> t2 (fp16) ---
// wave per node; lanes = 32 edge-slots x 2 half8-halves (32 rows in flight)

__global__ __launch_bounds__(256) void k_agg_mid(const int* __restrict__ node_start,
                                                 const int2* __restrict__ pay,
                                                 const float* __restrict__ dinv,
                                                 const __half* __restrict__ t1,
                                                 const float* __restrict__ bias,
                                                 const float* __restrict__ W2,
                                                 __half* __restrict__ t2) {
    __shared__ float w2s[HID * HID];
    int tid = threadIdx.x;
    w2s[tid] = W2[tid];
    __syncthreads();
    int i = (blockIdx.x * 256 + tid) >> 6;       // node id (grid exact)
    int lane = tid & 63;
    int eg = lane >> 1, q = lane & 1;
    int s = node_start[i], e2 = node_start[i + 1];
    const float4* t4 = (const float4*)t1;        // 16 B = half8 quadrant
    float acc[8] = {0.f, 0.f, 0.f, 0.f, 0.f, 0.f, 0.f, 0.f};
    for (int p = s + eg; p < e2; p += 32) {
        int2 pr = pay[p];
        float w = __int_as_float(pr.y);
        float4 v = t4[(pr.x << 1) + q];
        const __half2* hp = (const __half2*)&v;
#pragma unroll
        for (int j = 0; j < 4; ++j) {
            float2 f = __half22float2(hp[j]);
            acc[2 * j]     += w * f.x;
            acc[2 * j + 1] += w * f.y;
        }
    }
#pragma unroll
    for (int m = 2; m <= 32; m <<= 1) {
#pragma unroll
        for (int j = 0; j < 8; ++j) acc[j] += __shfl_xor(acc[j], m);
    }
    float d = dinv[i];
    float4 sv = t4[(i << 1) + q];
    const __half2* sp = (const __half2*)&sv;
    float4 b0 = ((const float4*)bias)[q * 2];
    float4 b1v = ((const float4*)bias)[q * 2 + 1];
    float bb[8] = {b0.x, b0.y, b0.z, b0.w, b1v.x, b1v.y, b1v.z, b1v.w};
    float hv[8];
#pragma unroll
    for (int j = 0; j < 4; ++j) {
        float2 f = __half22float2(sp[j]);
        hv[2 * j]     = fmaxf(d * (acc[2 * j] + f.x) + bb[2 * j], 0.f);
        hv[2 * j + 1] = fmaxf(d * (acc[2 * j + 1] + f.y) + bb[2 * j + 1], 0.f);
    }
    // broadcast full 16-value h row from lanes 0 (ch 0-7) and 1 (ch 8-15)
    float hk[16];
#pragma unroll
    for (int r = 0; r < 8; ++r) {
        hk[r]     = __shfl(hv[r], 0);
        hk[8 + r] = __shfl(hv[r], 1);
    }
    if (lane < 16) {
        float a2 = 0.f;
#pragma unroll
        for (int k = 0; k < HID; ++k) a2 += hk[k] * w2s[k * HID + lane];
        t2[(i << 4) + lane] = __float2half(d * a2);
    }
}

// ---------------- layer-2 aggregation + bias/relu + Wout dot -> out -----------

__global__ __launch_bounds__(256) void k_agg_out(const int* __restrict__ node_start,
                                                 const int2* __restrict__ pay,
                                                 const float* __restrict__ dinv,
                                                 const __half* __restrict__ t2,
                                                 const float* __restrict__ bias,
                                                 const float* __restrict__ Wout,
                                                 const float* __restrict__ bout,
                                                 float* __restrict__ out) {
    int tid = threadIdx.x;
    int i = (blockIdx.x * 256 + tid) >> 6;
    int lane = tid & 63;
    int eg = lane >> 1, q = lane & 1;
    int s = node_start[i], e2 = node_start[i + 1];
    const float4* t4 = (const float4*)t2;
    float acc[8] = {0.f, 0.f, 0.f, 0.f, 0.f, 0.f, 0.f, 0.f};
    for (int p = s + eg; p < e2; p += 32) {
        int2 pr = pay[p];
        float w = __int_as_float(pr.y);
        float4 v = t4[(pr.x << 1) + q];
        const __half2* hp = (const __half2*)&v;
#pragma unroll
        for (int j = 0; j < 4; ++j) {
            float2 f = __half22float2(hp[j]);
            acc[2 * j]     += w * f.x;
            acc[2 * j + 1] += w * f.y;
        }
    }
#pragma unroll
    for (int m = 2; m <= 32; m <<= 1) {
#pragma unroll
        for (int j = 0; j < 8; ++j) acc[j] += __shfl_xor(acc[j], m);
    }
    float d = dinv[i];
    float4 sv = t4[(i << 1) + q];
    const __half2* sp = (const __half2*)&sv;
    float4 b0 = ((const float4*)bias)[q * 2];
    float4 b1v = ((const float4*)bias)[q * 2 + 1];
    float bb[8] = {b0.x, b0.y, b0.z, b0.w, b1v.x, b1v.y, b1v.z, b1v.w};
    float4 w0 = ((const float4*)Wout)[q * 2];
    float4 w1v = ((const float4*)Wout)[q * 2 + 1];
    float wo[8] = {w0.x, w0.y, w0.z, w0.w, w1v.x, w1v.y, w1v.z, w1v.w};
    float r = 0.f;
#pragma unroll
    for (int j = 0; j < 4; ++j) {
        float2 f = __half22float2(sp[j]);
        r += fmaxf(d * (acc[2 * j] + f.x) + bb[2 * j], 0.f) * wo[2 * j];
        r += fmaxf(d * (acc[2 * j + 1] + f.y) + bb[2 * j + 1], 0.f) * wo[2 * j + 1];
    }
    r += __shfl_xor(r, 1);
    if (lane == 0) out[i] = r + bout[0];
}

extern "C" void kernel_launch(void* const* d_in, const int* in_sizes, int n_in,
                              void* d_out, int out_size, void* d_ws, size_t ws_size,
                              hipStream_t stream) {
    const float* x    = (const float*)d_in[0];
    const int*   eidx = (const int*)d_in[1];
    const float* ew   = (const float*)d_in[2];
    const float* W1   = (const float*)d_in[5];
    const float* b1   = (const float*)d_in[6];
    const float* W2   = (const float*)d_in[7];
    const float* b2   = (const float*)d_in[8];
    const float* Wout = (const float*)d_in[9];
    const float* bout = (const float*)d_in[10];
    float* out = (float*)d_out;

    const int* row = eidx;             // edge_index[0] (src)
    const int* col = eidx + N_EDGES;   // edge_index[1] (dst)

    // workspace (4B units). t1h aliases blkhist, t2h aliases offs (both dead
    // before the GEMM/agg phase writes them).
    int*    blkhist = (int*)d_ws;                    // NBLK*NBUK = 800768 ints
    __half* t1h     = (__half*)d_ws;                 // N*16 halves = 800000 ints
    int*    offs    = blkhist + NBLK * NBUK;         // 800768 ints
    __half* t2h     = (__half*)offs;                 // N*16 halves
    int*    total   = offs + NBLK * NBUK;            // 784
    int*    bstart  = total + 784;                   // 784
    float*  dinv    = (float*)(bstart + 784);        // N
    int*    nstart  = (int*)(dinv + N_NODES);        // N+4 (even pad)
    int2*   pay     = (int2*)(nstart + N_NODES + 4); // E int2 (8B-aligned)

    const int B = 256;
    const int gW = (N_NODES * 64) / B;               // 25000 exact (wave/node)

    // CSR build (two-level counting sort, no global atomics)
    k_hist1  <<<NBLK, B, 0, stream>>>(col, blkhist);
    k_colscan<<<NBUK, 1024, 0, stream>>>(blkhist, offs, total);
    k_bscan  <<<1, 1024, 0, stream>>>(total, bstart);
    k_place  <<<NBLK, B, 0, stream>>>(row, col, ew, offs, bstart, pay);
    k_sort2  <<<NBUK, B, 0, stream>>>(bstart, pay, nstart, dinv);

    // layer 1 GEMM (+dinv epilogue, fp16 out)
    k_gemm_in<<<N_NODES / 16, B, 0, stream>>>(x, W1, dinv, t1h);

    // layer 1 aggregation + relu + fused h@W2 (+dinv epilogue, fp16 out)
    k_agg_mid<<<gW, B, 0, stream>>>(nstart, pay, dinv, t1h, b1, W2, t2h);

    // layer 2 aggregation + relu + fused output projection
    k_agg_out<<<gW, B, 0, stream>>>(nstart, pay, dinv, t2h, b2, Wout, bout, out);
}

// Round 10
// 337.831 us; speedup vs baseline: 1.0685x; 1.0685x over previous
//
#include <hip/hip_runtime.h>
#include <hip/hip_fp16.h>

// GCN forward — two-level counting-sort CSR (no global atomics, coalesced
// placement) + fp16 gather table (L2-resident) + half4-quadrant wave-per-node
// aggregation (16 slots x 4 lanes, 2x unrolled -> 32 rows in flight).
// h@W2 and Wout fused in epilogues.
// N=100000, E=3200000, IN_C=128, HID=16, OUT=1.

constexpr int N_NODES = 100000;
constexpr int N_EDGES = 3200000;
constexpr int INC = 128;
constexpr int HID = 16;

constexpr int BSH  = 128;                       // nodes per bucket
constexpr int NBUK = (N_NODES + BSH - 1) / BSH; // 782
constexpr int NBLK = 1024;                      // edge-chunk blocks
constexpr int EPB  = N_EDGES / NBLK;            // 3125 edges/block (exact)
constexpr int BUFCAP = 6144;                    // LDS edge staging in sort2

// ---------------- pass 1: per-block LDS histogram (block-major out) -----------

__global__ __launch_bounds__(256) void k_hist1(const int* __restrict__ col,
                                               int* __restrict__ blkhist) {
    __shared__ int lh[NBUK];
    int tid = threadIdx.x, blk = blockIdx.x;
    for (int i = tid; i < NBUK; i += 256) lh[i] = 0;
    __syncthreads();
    int s = blk * EPB;
    for (int e = s + tid; e < s + EPB; e += 256)
        atomicAdd(&lh[col[e] >> 7], 1);          // LDS atomic
    __syncthreads();
    for (int i = tid; i < NBUK; i += 256)
        blkhist[blk * NBUK + i] = lh[i];         // coalesced
}

// ---------------- pass 2a: per-bucket scan over the 1024 block counts ---------

__global__ __launch_bounds__(1024) void k_colscan(const int* __restrict__ blkhist,
                                                  int* __restrict__ offs,
                                                  int* __restrict__ total) {
    __shared__ int sA[NBLK], sB[NBLK];
    int b = blockIdx.x, t = threadIdx.x;
    int v = blkhist[t * NBUK + b];
    sA[t] = v;
    __syncthreads();
    int* src = sA; int* dst = sB;
    for (int off = 1; off < NBLK; off <<= 1) {
        dst[t] = src[t] + ((t >= off) ? src[t - off] : 0);
        __syncthreads();
        int* tmp = src; src = dst; dst = tmp;
    }
    offs[b * NBLK + t] = src[t] - v;
    if (t == NBLK - 1) total[b] = src[NBLK - 1];
}

// ---------------- pass 2b: bucket starts (single block) ----------------

__global__ __launch_bounds__(1024) void k_bscan(const int* __restrict__ total,
                                                int* __restrict__ bstart) {
    __shared__ int s[1024];
    int t = threadIdx.x;
    int v = (t < NBUK) ? total[t] : 0;
    s[t] = v;
    __syncthreads();
    for (int off = 1; off < 1024; off <<= 1) {
        int u = (t >= off) ? s[t - off] : 0;
        __syncthreads();
        s[t] += u;
        __syncthreads();
    }
    if (t <= NBUK) bstart[t] = s[t] - v;         // bstart[NBUK] = E
}

// ---------------- pass 3: placement, LDS-staged bucket sort, coalesced out ----

__global__ __launch_bounds__(256) void k_place(const int* __restrict__ row,
                                               const int* __restrict__ col,
                                               const float* __restrict__ ew,
                                               const int* __restrict__ offs,
                                               const int* __restrict__ bstart,
                                               int2* __restrict__ pay) {
    __shared__ int2 spay[EPB];
    __shared__ unsigned short sbuk[EPB];
    __shared__ int lh[NBUK];
    __shared__ int gb[NBUK];
    __shared__ int sA[1024], sB[1024];
    int tid = threadIdx.x, blk = blockIdx.x;
    for (int i = tid; i < NBUK; i += 256) lh[i] = 0;
    __syncthreads();
    int s0 = blk * EPB;
    for (int j = tid; j < EPB; j += 256)
        atomicAdd(&lh[col[s0 + j] >> 7], 1);
    __syncthreads();
    for (int i = tid; i < 1024; i += 256) sA[i] = (i < NBUK) ? lh[i] : 0;
    __syncthreads();
    int* src = sA; int* dst = sB;
    for (int off = 1; off < 1024; off <<= 1) {
        for (int i = tid; i < 1024; i += 256)
            dst[i] = src[i] + ((i >= off) ? src[i - off] : 0);
        __syncthreads();
        int* tmp = src; src = dst; dst = tmp;
    }
    for (int i = tid; i < NBUK; i += 256) {
        int excl = src[i] - lh[i];
        gb[i] = bstart[i] + offs[i * NBLK + blk] - excl;
        lh[i] = excl;
    }
    __syncthreads();
    for (int j = tid; j < EPB; j += 256) {
        int e = s0 + j;
        int c = col[e];
        int b = c >> 7;
        int pos = atomicAdd(&lh[b], 1);
        spay[pos] = make_int2(((c & 127) << 17) | row[e], __float_as_int(ew[e]));
        sbuk[pos] = (unsigned short)b;
    }
    __syncthreads();
    for (int j = tid; j < EPB; j += 256) {
        int b = sbuk[j];
        pay[gb[b] + j] = spay[j];
    }
}

// ---------------- pass 4: in-bucket node sort (in place) + node_start + dinv --

__global__ __launch_bounds__(256) void k_sort2(const int* __restrict__ bstart,
                                               int2* __restrict__ pay,
                                               int* __restrict__ node_start,
                                               float* __restrict__ dinv) {
    __shared__ int2 buf[BUFCAP];
    __shared__ int cnt[BSH], sc[BSH], pos[BSH];
    __shared__ float dsum[BSH];
    int b = blockIdx.x, t = threadIdx.x;
    if (t < BSH) { cnt[t] = 0; dsum[t] = 1.0f; }   // 1.0 = self-loop weight
    __syncthreads();
    int s = bstart[b], e2 = bstart[b + 1];
    int m = e2 - s;
    for (int j = t; j < m; j += 256) {
        int2 pr = pay[s + j];
        buf[j] = pr;
        int d = pr.x >> 17;
        atomicAdd(&cnt[d], 1);
        atomicAdd(&dsum[d], __int_as_float(pr.y));
    }
    __syncthreads();
    int v = (t < BSH) ? cnt[t] : 0;
    if (t < BSH) sc[t] = v;
    __syncthreads();
    for (int off = 1; off < BSH; off <<= 1) {
        int u = (t >= off && t < BSH) ? sc[t - off] : 0;
        __syncthreads();
        if (t < BSH) sc[t] += u;
        __syncthreads();
    }
    if (t < BSH) {
        int excl = sc[t] - v;
        pos[t] = excl;
        int node = b * BSH + t;
        if (node <= N_NODES) node_start[node] = s + excl;
        if (node < N_NODES) dinv[node] = rsqrtf(dsum[t]);
    }
    if (t == 0 && b == 0) node_start[N_NODES] = N_EDGES;
    __syncthreads();
    for (int j = t; j < m; j += 256) {
        int2 pr = buf[j];
        int q = atomicAdd(&pos[pr.x >> 17], 1);
        pay[s + q] = make_int2(pr.x & 0x1FFFF, pr.y);
    }
}

// ---------------- GEMM x@W1, epilogue x dinv -> fp16: t1 = dinv ⊙ (x@W1) ------

__global__ __launch_bounds__(256) void k_gemm_in(const float* __restrict__ x,
                                                 const float* __restrict__ W1,
                                                 const float* __restrict__ dinv,
                                                 __half* __restrict__ t1) {
    __shared__ float ws[INC * HID];
    __shared__ float xs[16 * 129];
    int tid = threadIdx.x;
    int nb = blockIdx.x * 16;
    const float4* x4 = (const float4*)(x + (size_t)nb * INC);
    for (int j = tid; j < 512; j += 256) {
        float4 v = x4[j];
        int n = j >> 5, kq = (j & 31) << 2;
        float* d = &xs[n * 129 + kq];
        d[0] = v.x; d[1] = v.y; d[2] = v.z; d[3] = v.w;
    }
    for (int j = tid; j < 512; j += 256)
        ((float4*)ws)[j] = ((const float4*)W1)[j];
    __syncthreads();
    int ln = tid >> 4, c = tid & 15;
    float acc = 0.f;
#pragma unroll
    for (int k = 0; k < INC; ++k) acc += xs[ln * 129 + k] * ws[k * HID + c];
    int node = nb + ln;
    t1[(node << 4) + c] = __float2half(dinv[node] * acc);
}

// ---------------- layer-1 aggregation + bias/relu + fused h@W2 -> t2 (fp16) ---
// wave per node; lanes = 16 edge-slots x 4 half4-quadrants; 2x unrolled.

__global__ __launch_bounds__(256) void k_agg_mid(const int* __restrict__ node_start,
                                                 const int2* __restrict__ pay,
                                                 const float* __restrict__ dinv,
                                                 const __half* __restrict__ t1,
                                                 const float* __restrict__ bias,
                                                 const float* __restrict__ W2,
                                                 __half* __restrict__ t2) {
    __shared__ float w2s[HID * HID];
    int tid = threadIdx.x;
    w2s[tid] = W2[tid];
    __syncthreads();
    int i = (blockIdx.x * 256 + tid) >> 6;       // node id (grid exact)
    int lane = tid & 63;
    int eg = lane >> 2, q = lane & 3;            // edge-slot, quadrant
    int s = node_start[i], e2 = node_start[i + 1];
    const uint2* t8 = (const uint2*)t1;          // 8 B = half4 quadrant
    float acc[4] = {0.f, 0.f, 0.f, 0.f};
    int p = s + eg;
    for (; p + 16 < e2; p += 32) {
        int2 a0 = pay[p];
        int2 a1 = pay[p + 16];
        float w0 = __int_as_float(a0.y);
        float w1 = __int_as_float(a1.y);
        uint2 v0 = t8[(a0.x << 2) + q];
        uint2 v1 = t8[(a1.x << 2) + q];
        const __half2* h0 = (const __half2*)&v0;
        const __half2* h1 = (const __half2*)&v1;
#pragma unroll
        for (int j = 0; j < 2; ++j) {
            float2 f0 = __half22float2(h0[j]);
            float2 f1 = __half22float2(h1[j]);
            acc[2 * j]     += w0 * f0.x + w1 * f1.x;
            acc[2 * j + 1] += w0 * f0.y + w1 * f1.y;
        }
    }
    if (p < e2) {
        int2 a0 = pay[p];
        float w0 = __int_as_float(a0.y);
        uint2 v0 = t8[(a0.x << 2) + q];
        const __half2* h0 = (const __half2*)&v0;
#pragma unroll
        for (int j = 0; j < 2; ++j) {
            float2 f0 = __half22float2(h0[j]);
            acc[2 * j]     += w0 * f0.x;
            acc[2 * j + 1] += w0 * f0.y;
        }
    }
#pragma unroll
    for (int m = 4; m <= 32; m <<= 1) {
#pragma unroll
        for (int j = 0; j < 4; ++j) acc[j] += __shfl_xor(acc[j], m);
    }
    float d = dinv[i];
    uint2 sv = t8[(i << 2) + q];
    const __half2* sp = (const __half2*)&sv;
    float4 bb = ((const float4*)bias)[q];
    float hv[4];
    {
        float2 f0 = __half22float2(sp[0]);
        float2 f1 = __half22float2(sp[1]);
        hv[0] = fmaxf(d * (acc[0] + f0.x) + bb.x, 0.f);
        hv[1] = fmaxf(d * (acc[1] + f0.y) + bb.y, 0.f);
        hv[2] = fmaxf(d * (acc[2] + f1.x) + bb.z, 0.f);
        hv[3] = fmaxf(d * (acc[3] + f1.y) + bb.w, 0.f);
    }
    // broadcast full h row (lane j of 0..3 holds quadrant j)
    float hk[16];
#pragma unroll
    for (int j = 0; j < 4; ++j) {
#pragma unroll
        for (int r = 0; r < 4; ++r) hk[j * 4 + r] = __shfl(hv[r], j);
    }
    if (lane < 16) {
        float a2 = 0.f;
#pragma unroll
        for (int k = 0; k < HID; ++k) a2 += hk[k] * w2s[k * HID + lane];
        t2[(i << 4) + lane] = __float2half(d * a2);
    }
}

// ---------------- layer-2 aggregation + bias/relu + Wout dot -> out -----------

__global__ __launch_bounds__(256) void k_agg_out(const int* __restrict__ node_start,
                                                 const int2* __restrict__ pay,
                                                 const float* __restrict__ dinv,
                                                 const __half* __restrict__ t2,
                                                 const float* __restrict__ bias,
                                                 const float* __restrict__ Wout,
                                                 const float* __restrict__ bout,
                                                 float* __restrict__ out) {
    int tid = threadIdx.x;
    int i = (blockIdx.x * 256 + tid) >> 6;
    int lane = tid & 63;
    int eg = lane >> 2, q = lane & 3;
    int s = node_start[i], e2 = node_start[i + 1];
    const uint2* t8 = (const uint2*)t2;
    float acc[4] = {0.f, 0.f, 0.f, 0.f};
    int p = s + eg;
    for (; p + 16 < e2; p += 32) {
        int2 a0 = pay[p];
        int2 a1 = pay[p + 16];
        float w0 = __int_as_float(a0.y);
        float w1 = __int_as_float(a1.y);
        uint2 v0 = t8[(a0.x << 2) + q];
        uint2 v1 = t8[(a1.x << 2) + q];
        const __half2* h0 = (const __half2*)&v0;
        const __half2* h1 = (const __half2*)&v1;
#pragma unroll
        for (int j = 0; j < 2; ++j) {
            float2 f0 = __half22float2(h0[j]);
            float2 f1 = __half22float2(h1[j]);
            acc[2 * j]     += w0 * f0.x + w1 * f1.x;
            acc[2 * j + 1] += w0 * f0.y + w1 * f1.y;
        }
    }
    if (p < e2) {
        int2 a0 = pay[p];
        float w0 = __int_as_float(a0.y);
        uint2 v0 = t8[(a0.x << 2) + q];
        const __half2* h0 = (const __half2*)&v0;
#pragma unroll
        for (int j = 0; j < 2; ++j) {
            float2 f0 = __half22float2(h0[j]);
            acc[2 * j]     += w0 * f0.x;
            acc[2 * j + 1] += w0 * f0.y;
        }
    }
#pragma unroll
    for (int m = 4; m <= 32; m <<= 1) {
#pragma unroll
        for (int j = 0; j < 4; ++j) acc[j] += __shfl_xor(acc[j], m);
    }
    float d = dinv[i];
    uint2 sv = t8[(i << 2) + q];
    const __half2* sp = (const __half2*)&sv;
    float4 bb = ((const float4*)bias)[q];
    float4 wo = ((const float4*)Wout)[q];
    float r;
    {
        float2 f0 = __half22float2(sp[0]);
        float2 f1 = __half22float2(sp[1]);
        r = fmaxf(d * (acc[0] + f0.x) + bb.x, 0.f) * wo.x
          + fmaxf(d * (acc[1] + f0.y) + bb.y, 0.f) * wo.y
          + fmaxf(d * (acc[2] + f1.x) + bb.z, 0.f) * wo.z
          + fmaxf(d * (acc[3] + f1.y) + bb.w, 0.f) * wo.w;
    }
    r += __shfl_xor(r, 1);
    r += __shfl_xor(r, 2);
    if (lane == 0) out[i] = r + bout[0];
}

extern "C" void kernel_launch(void* const* d_in, const int* in_sizes, int n_in,
                              void* d_out, int out_size, void* d_ws, size_t ws_size,
                              hipStream_t stream) {
    const float* x    = (const float*)d_in[0];
    const int*   eidx = (const int*)d_in[1];
    const float* ew   = (const float*)d_in[2];
    const float* W1   = (const float*)d_in[5];
    const float* b1   = (const float*)d_in[6];
    const float* W2   = (const float*)d_in[7];
    const float* b2   = (const float*)d_in[8];
    const float* Wout = (const float*)d_in[9];
    const float* bout = (const float*)d_in[10];
    float* out = (float*)d_out;

    const int* row = eidx;             // edge_index[0] (src)
    const int* col = eidx + N_EDGES;   // edge_index[1] (dst)

    // workspace (4B units). t1h aliases blkhist, t2h aliases offs (both dead
    // before the GEMM/agg phase writes them).
    int*    blkhist = (int*)d_ws;                    // NBLK*NBUK = 800768 ints
    __half* t1h     = (__half*)d_ws;                 // N*16 halves = 800000 ints
    int*    offs    = blkhist + NBLK * NBUK;         // 800768 ints
    __half* t2h     = (__half*)offs;                 // N*16 halves
    int*    total   = offs + NBLK * NBUK;            // 784
    int*    bstart  = total + 784;                   // 784
    float*  dinv    = (float*)(bstart + 784);        // N
    int*    nstart  = (int*)(dinv + N_NODES);        // N+4 (even pad)
    int2*   pay     = (int2*)(nstart + N_NODES + 4); // E int2 (8B-aligned)

    const int B = 256;
    const int gW = (N_NODES * 64) / B;               // 25000 exact (wave/node)

    // CSR build (two-level counting sort, no global atomics)
    k_hist1  <<<NBLK, B, 0, stream>>>(col, blkhist);
    k_colscan<<<NBUK, 1024, 0, stream>>>(blkhist, offs, total);
    k_bscan  <<<1, 1024, 0, stream>>>(total, bstart);
    k_place  <<<NBLK, B, 0, stream>>>(row, col, ew, offs, bstart, pay);
    k_sort2  <<<NBUK, B, 0, stream>>>(bstart, pay, nstart, dinv);

    // layer 1 GEMM (+dinv epilogue, fp16 out)
    k_gemm_in<<<N_NODES / 16, B, 0, stream>>>(x, W1, dinv, t1h);

    // layer 1 aggregation + relu + fused h@W2 (+dinv epilogue, fp16 out)
    k_agg_mid<<<gW, B, 0, stream>>>(nstart, pay, dinv, t1h, b1, W2, t2h);

    // layer 2 aggregation + relu + fused output projection
    k_agg_out<<<gW, B, 0, stream>>>(nstart, pay, dinv, t2h, b2, Wout, bout, out);
}